// Round 3
// baseline (73383.472 us; speedup 1.0000x reference)
//
#include <hip/hip_runtime.h>

__device__ __forceinline__ float sigf(float x){ return 1.0f/(1.0f + __expf(-x)); }
__device__ __forceinline__ float tanhfast(float x){ float t = __expf(2.0f*x); return 1.0f - 2.0f/(t + 1.0f); }

__device__ __forceinline__ float bf2f(unsigned short u){
  union { unsigned int i; float f; } v; v.i = ((unsigned int)u) << 16; return v.f;
}
__device__ __forceinline__ float u2f(unsigned int i){
  union { unsigned int i; float f; } v; v.i = i; return v.f;
}
__device__ __forceinline__ unsigned short f2bf(float f){
  union { float f; unsigned int i; } v; v.f = f;
  unsigned int x = v.i + 0x7fffu + ((v.i >> 16) & 1u);
  return (unsigned short)(x >> 16);
}

// ============ prep: weight converts ============
// w1b[n][k], K=1536: k<512 -> iw1[n*512+k], else hw1[n*1024+k-512]
__global__ __launch_bounds__(256) void k_w1(const float* __restrict__ iw1, const float* __restrict__ hw1,
                                            ushort* __restrict__ w1b){
  int idx4 = (blockIdx.x*256 + threadIdx.x) * 4;       // 4096*1536 elems
  int n = idx4 / 1536, k = idx4 % 1536;
  float4 v = (k < 512) ? *(const float4*)(iw1 + n*512 + k)
                       : *(const float4*)(hw1 + n*1024 + (k - 512));
  ushort4 o; o.x=f2bf(v.x); o.y=f2bf(v.y); o.z=f2bf(v.z); o.w=f2bf(v.w);
  *(ushort4*)(w1b + idx4) = o;
}
// w2b[n][k], n<1024 -> h2a[n*1024+k], else hw2[(n-1024)*1024+k]; 5120x1024
__global__ __launch_bounds__(256) void k_w2(const float* __restrict__ h2a, const float* __restrict__ hw2,
                                            ushort* __restrict__ w2b){
  int idx4 = (blockIdx.x*256 + threadIdx.x) * 4;
  int n = idx4 >> 10, k = idx4 & 1023;
  float4 v = (n < 1024) ? *(const float4*)(h2a + n*1024 + k)
                        : *(const float4*)(hw2 + (n-1024)*1024 + k);
  ushort4 o; o.x=f2bf(v.x); o.y=f2bf(v.y); o.z=f2bf(v.z); o.w=f2bf(v.w);
  *(ushort4*)(w2b + idx4) = o;
}
// w3b = iw2 bf16, 4096x1024
__global__ __launch_bounds__(256) void k_w3(const float* __restrict__ iw2, ushort* __restrict__ w3b){
  int idx4 = (blockIdx.x*256 + threadIdx.x) * 4;
  float4 v = *(const float4*)(iw2 + idx4);
  ushort4 o; o.x=f2bf(v.x); o.y=f2bf(v.y); o.z=f2bf(v.z); o.w=f2bf(v.w);
  *(ushort4*)(w3b + idx4) = o;
}
// ctxb[b][s][c] bf16 from ctx[s][b][c] f32
__global__ __launch_bounds__(256) void k_ctxT(const float* __restrict__ ctx, ushort* __restrict__ ctxb){
  int idx4 = (blockIdx.x*256 + threadIdx.x) * 4;       // out index, 64*256*1024 elems
  int c = idx4 & 1023, s = (idx4 >> 10) & 255, b = idx4 >> 18;
  float4 v = *(const float4*)(ctx + (s*64 + b)*1024 + c);
  ushort4 o; o.x=f2bf(v.x); o.y=f2bf(v.y); o.z=f2bf(v.z); o.w=f2bf(v.w);
  *(ushort4*)(ctxb + idx4) = o;
}

// ============ prep: pc / pi GEMMs (write bf16) ============
__global__ __launch_bounds__(256) void k_pc(const float* __restrict__ ctxp, const float* __restrict__ c2a,
                                            const float* __restrict__ bc, ushort* __restrict__ pcb){
  __shared__ __align__(16) float As[32][68];
  __shared__ __align__(16) float Bs[32][68];
  const int tid = threadIdx.x;
  const int m0 = blockIdx.x * 64;
  const int n0 = blockIdx.y * 64;
  const int tx = tid & 15, ty = tid >> 4;
  float acc[4][4] = {};
  for (int k0 = 0; k0 < 1024; k0 += 32){
#pragma unroll
    for (int l = 0; l < 8; ++l){
      int idx = l*256 + tid; int m = idx >> 5, k = idx & 31;
      As[k][m] = ctxp[(m0+m)*1024 + k0 + k];
    }
#pragma unroll
    for (int l = 0; l < 8; ++l){
      int idx = l*256 + tid; int k = idx >> 6, n = idx & 63;
      Bs[k][n] = c2a[(k0+k)*1024 + n0 + n];
    }
    __syncthreads();
#pragma unroll
    for (int k = 0; k < 32; ++k){
      float4 a4 = *(const float4*)&As[k][4*ty];
      float4 b4 = *(const float4*)&Bs[k][4*tx];
      float av[4] = {a4.x, a4.y, a4.z, a4.w};
      float bv[4] = {b4.x, b4.y, b4.z, b4.w};
#pragma unroll
      for (int i = 0; i < 4; ++i)
#pragma unroll
        for (int j = 0; j < 4; ++j) acc[i][j] = fmaf(av[i], bv[j], acc[i][j]);
    }
    __syncthreads();
  }
#pragma unroll
  for (int i = 0; i < 4; ++i){
    int m = m0 + 4*ty + i;
    int n = n0 + 4*tx;
    ushort4 o;
    o.x = f2bf(acc[i][0] + bc[n]);
    o.y = f2bf(acc[i][1] + bc[n+1]);
    o.z = f2bf(acc[i][2] + bc[n+2]);
    o.w = f2bf(acc[i][3] + bc[n+3]);
    *(ushort4*)(pcb + m*1024 + n) = o;
  }
}

__global__ __launch_bounds__(256) void k_pi(const float* __restrict__ inp, const float* __restrict__ i2a,
                                            ushort* __restrict__ pib){
  __shared__ __align__(16) float As[32][68];
  __shared__ __align__(16) float Bs[32][68];
  const int tid = threadIdx.x;
  const int t = blockIdx.x;
  const int n0 = blockIdx.y * 64;
  const int tx = tid & 15, ty = tid >> 4;
  float acc[4][4] = {};
  for (int k0 = 0; k0 < 512; k0 += 32){
#pragma unroll
    for (int l = 0; l < 8; ++l){
      int idx = l*256 + tid; int m = idx >> 5, k = idx & 31;
      As[k][m] = inp[(m*256 + t)*512 + k0 + k];
    }
#pragma unroll
    for (int l = 0; l < 8; ++l){
      int idx = l*256 + tid; int k = idx >> 6, n = idx & 63;
      Bs[k][n] = i2a[(k0+k)*1024 + n0 + n];
    }
    __syncthreads();
#pragma unroll
    for (int k = 0; k < 32; ++k){
      float4 a4 = *(const float4*)&As[k][4*ty];
      float4 b4 = *(const float4*)&Bs[k][4*tx];
      float av[4] = {a4.x, a4.y, a4.z, a4.w};
      float bv[4] = {b4.x, b4.y, b4.z, b4.w};
#pragma unroll
      for (int i = 0; i < 4; ++i)
#pragma unroll
        for (int j = 0; j < 4; ++j) acc[i][j] = fmaf(av[i], bv[j], acc[i][j]);
    }
    __syncthreads();
  }
#pragma unroll
  for (int i = 0; i < 4; ++i){
    int m = 4*ty + i;
    int n = n0 + 4*tx;
    ushort4 o; o.x=f2bf(acc[i][0]); o.y=f2bf(acc[i][1]); o.z=f2bf(acc[i][2]); o.w=f2bf(acc[i][3]);
    *(ushort4*)(pib + (t*64 + m)*1024 + n) = o;
  }
}

// ============ per-step kernels ============
// K1: gates1 = [x_t|hx] @ w1b^T + ib1 + hb1   (A f32, W bf16)
__global__ __launch_bounds__(256) void k_gates1(const float* __restrict__ inp, const float* __restrict__ hxb,
                                                const ushort* __restrict__ w1b,
                                                const float* __restrict__ ib1, const float* __restrict__ hb1,
                                                float* __restrict__ gates1, int t){
  __shared__ __align__(16) float As[32][68];
  __shared__ __align__(16) float Ws[32][36];
  const int tid = threadIdx.x;
  const int nb = blockIdx.x * 32;
  const int tx = tid & 15, ty = tid >> 4;
  float acc[4][2] = {};
  for (int k0 = 0; k0 < 1536; k0 += 32){
#pragma unroll
    for (int l = 0; l < 8; ++l){
      int idx = l*256 + tid; int m = idx >> 5, k = idx & 31;
      int kg = k0 + k;
      As[k][m] = (kg < 512) ? inp[(m*256 + t)*512 + kg] : hxb[m*1024 + kg - 512];
    }
#pragma unroll
    for (int l = 0; l < 2; ++l){
      int e = l*256 + tid;          // 0..511
      int n = e >> 4;               // 0..31
      int k = (e & 15) * 2;         // 0..30
      unsigned int u = *(const unsigned int*)(w1b + (nb+n)*1536 + k0 + k);
      Ws[k][n]   = u2f(u << 16);
      Ws[k+1][n] = u2f(u & 0xffff0000u);
    }
    __syncthreads();
#pragma unroll
    for (int k = 0; k < 32; ++k){
      float4 a4 = *(const float4*)&As[k][4*ty];
      float2 w2 = *(const float2*)&Ws[k][2*tx];
      float av[4] = {a4.x, a4.y, a4.z, a4.w};
      float wv[2] = {w2.x, w2.y};
#pragma unroll
      for (int i = 0; i < 4; ++i)
#pragma unroll
        for (int j = 0; j < 2; ++j) acc[i][j] = fmaf(av[i], wv[j], acc[i][j]);
    }
    __syncthreads();
  }
#pragma unroll
  for (int i = 0; i < 4; ++i){
    int m = 4*ty + i;
#pragma unroll
    for (int j = 0; j < 2; ++j){
      int n = nb + 2*tx + j;
      gates1[m*4096 + n] = acc[i][j] + ib1[n] + hb1[n];
    }
  }
}

// LSTM1 pointwise -> hy, cym
__global__ __launch_bounds__(256) void k_lstm1(const float* __restrict__ gates, const float* __restrict__ cxb,
                                               float* __restrict__ hy, float* __restrict__ cym){
  int idx = blockIdx.x * 256 + threadIdx.x;
  int b = idx >> 10, h = idx & 1023;
  const float* g = gates + b*4096;
  float gi = g[h], gf = g[h+1024], gg = g[h+2048], go = g[h+3072];
  float c = sigf(gf)*cxb[idx] + sigf(gi)*tanhfast(gg);
  cym[idx] = c;
  hy[idx] = sigf(go)*tanhfast(c);
}

// K2: n<1024: q[b][n] = hy·h2a[n] + pi[t,b,n] ; else g2h[b][n-1024] = hy·hw2[n-1024]
__global__ __launch_bounds__(256) void k_hyproj(const float* __restrict__ hy, const ushort* __restrict__ w2b,
                                                const ushort* __restrict__ pib,
                                                float* __restrict__ q, float* __restrict__ g2h, int t){
  __shared__ __align__(16) float As[32][68];
  __shared__ __align__(16) float Ws[32][36];
  const int tid = threadIdx.x;
  const int nb = blockIdx.x * 32;
  const int tx = tid & 15, ty = tid >> 4;
  float acc[4][2] = {};
  for (int k0 = 0; k0 < 1024; k0 += 32){
#pragma unroll
    for (int l = 0; l < 8; ++l){
      int idx = l*256 + tid; int m = idx >> 5, k = idx & 31;
      As[k][m] = hy[m*1024 + k0 + k];
    }
#pragma unroll
    for (int l = 0; l < 2; ++l){
      int e = l*256 + tid;
      int n = e >> 4;
      int k = (e & 15) * 2;
      unsigned int u = *(const unsigned int*)(w2b + (nb+n)*1024 + k0 + k);
      Ws[k][n]   = u2f(u << 16);
      Ws[k+1][n] = u2f(u & 0xffff0000u);
    }
    __syncthreads();
#pragma unroll
    for (int k = 0; k < 32; ++k){
      float4 a4 = *(const float4*)&As[k][4*ty];
      float2 w2 = *(const float2*)&Ws[k][2*tx];
      float av[4] = {a4.x, a4.y, a4.z, a4.w};
      float wv[2] = {w2.x, w2.y};
#pragma unroll
      for (int i = 0; i < 4; ++i)
#pragma unroll
        for (int j = 0; j < 2; ++j) acc[i][j] = fmaf(av[i], wv[j], acc[i][j]);
    }
    __syncthreads();
  }
#pragma unroll
  for (int i = 0; i < 4; ++i){
    int m = 4*ty + i;
#pragma unroll
    for (int j = 0; j < 2; ++j){
      int ng = nb + 2*tx + j;
      if (ng < 1024) q[m*1024 + ng] = acc[i][j] + bf2f(pib[(t*64 + m)*1024 + ng]);
      else           g2h[m*4096 + ng - 1024] = acc[i][j];
    }
  }
}

// K3a: logits[b][s] = sum_c tanh(pcb[s,b,c] + q[b,c]) * r[c]   (pcb bf16)
__global__ __launch_bounds__(256) void k_logits(const ushort* __restrict__ pcb, const float* __restrict__ q,
                                                const float* __restrict__ r2a, float* __restrict__ logits){
  const int w = threadIdx.x >> 6, lane = threadIdx.x & 63;
  const int p = blockIdx.x*4 + w;
  const int s = p >> 6, b = p & 63;
  const ushort* pp = pcb + (s*64 + b)*1024;
  const float* qp = q + b*1024;
  float acc = 0.0f;
#pragma unroll
  for (int half = 0; half < 2; ++half){
    int cb = lane*8 + half*512;
    uint4 pv = *(const uint4*)(pp + cb);
    float4 q0 = *(const float4*)(qp + cb);
    float4 q1 = *(const float4*)(qp + cb + 4);
    float4 r0 = *(const float4*)(r2a + cb);
    float4 r1 = *(const float4*)(r2a + cb + 4);
    acc = fmaf(tanhfast(u2f(pv.x << 16)        + q0.x), r0.x, acc);
    acc = fmaf(tanhfast(u2f(pv.x & 0xffff0000u)+ q0.y), r0.y, acc);
    acc = fmaf(tanhfast(u2f(pv.y << 16)        + q0.z), r0.z, acc);
    acc = fmaf(tanhfast(u2f(pv.y & 0xffff0000u)+ q0.w), r0.w, acc);
    acc = fmaf(tanhfast(u2f(pv.z << 16)        + q1.x), r1.x, acc);
    acc = fmaf(tanhfast(u2f(pv.z & 0xffff0000u)+ q1.y), r1.y, acc);
    acc = fmaf(tanhfast(u2f(pv.w << 16)        + q1.z), r1.z, acc);
    acc = fmaf(tanhfast(u2f(pv.w & 0xffff0000u)+ q1.w), r1.w, acc);
  }
#pragma unroll
  for (int off = 32; off; off >>= 1) acc += __shfl_xor(acc, off);
  if (lane == 0) logits[b*256 + s] = acc;
}

// K3b: softmax (redundant per chunk) + partial wctx over 32-s chunk (ctx bf16, transposed)
__global__ __launch_bounds__(256) void k_attnout(const float* __restrict__ logits, const ushort* __restrict__ ctxb,
                                                 float* __restrict__ partial){
  __shared__ float red[256];
  __shared__ float sm[256];
  __shared__ float al[32];
  const int bi = blockIdx.x >> 3, ch = blockIdx.x & 7;
  const int tid = threadIdx.x;
  float l = logits[bi*256 + tid];
  red[tid] = l; __syncthreads();
  for (int s = 128; s; s >>= 1){ if (tid < s) red[tid] = fmaxf(red[tid], red[tid+s]); __syncthreads(); }
  float mx = red[0]; __syncthreads();
  float e = __expf(l - mx);
  sm[tid] = e; red[tid] = e; __syncthreads();
  for (int s = 128; s; s >>= 1){ if (tid < s) red[tid] += red[tid+s]; __syncthreads(); }
  float inv = 1.0f / red[0];
  if (tid < 32) al[tid] = sm[ch*32 + tid] * inv;
  __syncthreads();
  const int c0 = tid * 4;
  const ushort* cp = ctxb + (bi*256 + ch*32)*1024 + c0;
  float a0=0.f, a1=0.f, a2=0.f, a3=0.f;
#pragma unroll 4
  for (int s = 0; s < 32; ++s){
    ushort4 v = *(const ushort4*)(cp + s*1024);
    float aw = al[s];
    a0 = fmaf(aw, bf2f(v.x), a0);
    a1 = fmaf(aw, bf2f(v.y), a1);
    a2 = fmaf(aw, bf2f(v.z), a2);
    a3 = fmaf(aw, bf2f(v.w), a3);
  }
  float4 o; o.x=a0; o.y=a1; o.z=a2; o.w=a3;
  *(float4*)(partial + (ch*64 + bi)*1024 + c0) = o;
}

// reduce 8 partials -> wctx
__global__ __launch_bounds__(256) void k_wctxred(const float* __restrict__ partial, float* __restrict__ wctx){
  int i4 = (blockIdx.x*256 + threadIdx.x) * 4;
  float4 s = *(const float4*)(partial + i4);
#pragma unroll
  for (int ch = 1; ch < 8; ++ch){
    float4 v = *(const float4*)(partial + ch*65536 + i4);
    s.x += v.x; s.y += v.y; s.z += v.z; s.w += v.w;
  }
  *(float4*)(wctx + i4) = s;
}

// K4: gates2 = wctx @ w3b^T + g2h + ib2 + hb2
__global__ __launch_bounds__(256) void k_gates2(const float* __restrict__ wctx, const ushort* __restrict__ w3b,
                                                const float* __restrict__ g2h,
                                                const float* __restrict__ ib2, const float* __restrict__ hb2,
                                                float* __restrict__ gates2){
  __shared__ __align__(16) float As[32][68];
  __shared__ __align__(16) float Ws[32][36];
  const int tid = threadIdx.x;
  const int nb = blockIdx.x * 32;
  const int tx = tid & 15, ty = tid >> 4;
  float acc[4][2] = {};
  for (int k0 = 0; k0 < 1024; k0 += 32){
#pragma unroll
    for (int l = 0; l < 8; ++l){
      int idx = l*256 + tid; int m = idx >> 5, k = idx & 31;
      As[k][m] = wctx[m*1024 + k0 + k];
    }
#pragma unroll
    for (int l = 0; l < 2; ++l){
      int e = l*256 + tid;
      int n = e >> 4;
      int k = (e & 15) * 2;
      unsigned int u = *(const unsigned int*)(w3b + (nb+n)*1024 + k0 + k);
      Ws[k][n]   = u2f(u << 16);
      Ws[k+1][n] = u2f(u & 0xffff0000u);
    }
    __syncthreads();
#pragma unroll
    for (int k = 0; k < 32; ++k){
      float4 a4 = *(const float4*)&As[k][4*ty];
      float2 w2 = *(const float2*)&Ws[k][2*tx];
      float av[4] = {a4.x, a4.y, a4.z, a4.w};
      float wv[2] = {w2.x, w2.y};
#pragma unroll
      for (int i = 0; i < 4; ++i)
#pragma unroll
        for (int j = 0; j < 2; ++j) acc[i][j] = fmaf(av[i], wv[j], acc[i][j]);
    }
    __syncthreads();
  }
#pragma unroll
  for (int i = 0; i < 4; ++i){
    int m = 4*ty + i;
#pragma unroll
    for (int j = 0; j < 2; ++j){
      int n = nb + 2*tx + j;
      gates2[m*4096 + n] = acc[i][j] + g2h[m*4096 + n] + ib2[n] + hb2[n];
    }
  }
}

// LSTM2 pointwise -> output[t], hxb, cxb
__global__ __launch_bounds__(256) void k_lstm2(const float* __restrict__ gates, const float* __restrict__ cym,
                                               float* __restrict__ out, float* __restrict__ hxb,
                                               float* __restrict__ cxb, int t){
  int idx = blockIdx.x * 256 + threadIdx.x;
  int b = idx >> 10, h = idx & 1023;
  const float* g = gates + b*4096;
  float gi = g[h], gf = g[h+1024], gg = g[h+2048], go = g[h+3072];
  float c = sigf(gf)*cym[idx] + sigf(gi)*tanhfast(gg);
  float hv = sigf(go)*tanhfast(c);
  out[t*65536 + idx] = hv;
  hxb[idx] = hv;
  cxb[idx] = c;
}

extern "C" void kernel_launch(void* const* d_in, const int* in_sizes, int n_in,
                              void* d_out, int out_size, void* d_ws, size_t ws_size,
                              hipStream_t stream) {
  const float* input = (const float*)d_in[0];
  const float* hx    = (const float*)d_in[1];
  const float* cx    = (const float*)d_in[2];
  const float* ctxp  = (const float*)d_in[3];
  const float* iw1   = (const float*)d_in[4];
  const float* hw1   = (const float*)d_in[5];
  const float* ib1   = (const float*)d_in[6];
  const float* hb1   = (const float*)d_in[7];
  const float* iw2   = (const float*)d_in[8];
  const float* hw2   = (const float*)d_in[9];
  const float* ib2   = (const float*)d_in[10];
  const float* hb2   = (const float*)d_in[11];
  const float* c2a   = (const float*)d_in[12];
  const float* b_c2a = (const float*)d_in[13];
  const float* h2a   = (const float*)d_in[14];
  const float* i2a   = (const float*)d_in[15];
  const float* r2a   = (const float*)d_in[16];
  float* out = (float*)d_out;

  char* base = (char*)d_ws;
  ushort* pcb    = (ushort*)(base);                     // 33,554,432 B
  ushort* ctxb   = (ushort*)(base + 33554432);          // 33,554,432
  ushort* pib    = (ushort*)(base + 67108864);          // 33,554,432
  ushort* w1b    = (ushort*)(base + 100663296);         // 12,582,912
  ushort* w2b    = (ushort*)(base + 113246208);         // 10,485,760
  ushort* w3b    = (ushort*)(base + 123731968);         //  8,388,608
  float*  gates1 = (float*)(base + 132120576);          //  1,048,576
  float*  g2h    = (float*)(base + 133169152);          //  1,048,576
  float*  gates2 = (float*)(base + 134217728);          //  1,048,576
  float*  hy     = (float*)(base + 135266304);          //    262,144
  float*  cym    = (float*)(base + 135528448);
  float*  q      = (float*)(base + 135790592);
  float*  wctx   = (float*)(base + 136052736);
  float*  hxb    = (float*)(base + 136314880);
  float*  cxb    = (float*)(base + 136577024);
  float*  logits = (float*)(base + 136839168);          //     65,536
  float*  partial= (float*)(base + 136904704);          //  2,097,152  (end 139,001,856)

  hipMemcpyAsync(hxb, hx, 65536*sizeof(float), hipMemcpyDeviceToDevice, stream);
  hipMemcpyAsync(cxb, cx, 65536*sizeof(float), hipMemcpyDeviceToDevice, stream);

  // prep (once per launch)
  k_w1  <<<6144, 256, 0, stream>>>(iw1, hw1, w1b);
  k_w2  <<<5120, 256, 0, stream>>>(h2a, hw2, w2b);
  k_w3  <<<4096, 256, 0, stream>>>(iw2, w3b);
  k_ctxT<<<16384,256, 0, stream>>>(ctxp, ctxb);
  k_pc  <<<dim3(256,16), 256, 0, stream>>>(ctxp, c2a, b_c2a, pcb);
  k_pi  <<<dim3(256,16), 256, 0, stream>>>(input, i2a, pib);

  for (int t = 0; t < 256; ++t){
    k_gates1 <<<128, 256, 0, stream>>>(input, hxb, w1b, ib1, hb1, gates1, t);
    k_lstm1  <<<256, 256, 0, stream>>>(gates1, cxb, hy, cym);
    k_hyproj <<<160, 256, 0, stream>>>(hy, w2b, pib, q, g2h, t);
    k_logits <<<4096,256, 0, stream>>>(pcb, q, r2a, logits);
    k_attnout<<<512, 256, 0, stream>>>(logits, ctxb, partial);
    k_wctxred<<<64,  256, 0, stream>>>(partial, wctx);
    k_gates2 <<<128, 256, 0, stream>>>(wctx, w3b, g2h, ib2, hb2, gates2);
    k_lstm2  <<<256, 256, 0, stream>>>(gates2, cym, out, hxb, cxb, t);
  }

  hipMemcpyAsync(out + 16777216,         hxb, 65536*sizeof(float), hipMemcpyDeviceToDevice, stream);
  hipMemcpyAsync(out + 16777216 + 65536, cxb, 65536*sizeof(float), hipMemcpyDeviceToDevice, stream);
}

// Round 4
// 16230.225 us; speedup vs baseline: 4.5214x; 4.5214x over previous
//
#include <hip/hip_runtime.h>

typedef __attribute__((ext_vector_type(8))) short short8v;
typedef __attribute__((ext_vector_type(4))) float f32x4;

#define MFMA(a,b,c) __builtin_amdgcn_mfma_f32_16x16x32_bf16((a),(b),(c),0,0,0)

__device__ __forceinline__ float rcpf_(float x){ return __builtin_amdgcn_rcpf(x); }
__device__ __forceinline__ float sigf(float x){ return rcpf_(1.0f + __expf(-x)); }
__device__ __forceinline__ float tanhfast(float x){ return fmaf(-2.0f, rcpf_(1.0f + __expf(2.0f*x)), 1.0f); }
__device__ __forceinline__ float bf2f(unsigned short u){ union{unsigned int i; float f;} v; v.i = ((unsigned int)u)<<16; return v.f; }
__device__ __forceinline__ float u2f(unsigned int i){ union{unsigned int i; float f;} v; v.i = i; return v.f; }
__device__ __forceinline__ unsigned short f2bf(float f){ union{float f; unsigned int i;} v; v.f=f; unsigned int x = v.i + 0x7fffu + ((v.i>>16)&1u); return (unsigned short)(x>>16); }
__device__ __forceinline__ float4 ld4(const float* p){ return *(const float4*)p; }

// ============ prep: weight converts ============
__global__ __launch_bounds__(256) void k_w1(const float* __restrict__ iw1, const float* __restrict__ hw1,
                                            ushort* __restrict__ w1b){
  int idx4 = (blockIdx.x*256 + threadIdx.x) * 4;       // 4096*1536
  int n = idx4 / 1536, k = idx4 % 1536;
  float4 v = (k < 512) ? *(const float4*)(iw1 + n*512 + k)
                       : *(const float4*)(hw1 + n*1024 + (k - 512));
  ushort4 o; o.x=f2bf(v.x); o.y=f2bf(v.y); o.z=f2bf(v.z); o.w=f2bf(v.w);
  *(ushort4*)(w1b + idx4) = o;
}
__global__ __launch_bounds__(256) void k_w2(const float* __restrict__ h2a, const float* __restrict__ hw2,
                                            ushort* __restrict__ w2b){
  int idx4 = (blockIdx.x*256 + threadIdx.x) * 4;       // 5120*1024
  int n = idx4 >> 10, k = idx4 & 1023;
  float4 v = (n < 1024) ? *(const float4*)(h2a + n*1024 + k)
                        : *(const float4*)(hw2 + (n-1024)*1024 + k);
  ushort4 o; o.x=f2bf(v.x); o.y=f2bf(v.y); o.z=f2bf(v.z); o.w=f2bf(v.w);
  *(ushort4*)(w2b + idx4) = o;
}
__global__ __launch_bounds__(256) void k_w3(const float* __restrict__ iw2, ushort* __restrict__ w3b){
  int idx4 = (blockIdx.x*256 + threadIdx.x) * 4;       // 4096*1024
  float4 v = *(const float4*)(iw2 + idx4);
  ushort4 o; o.x=f2bf(v.x); o.y=f2bf(v.y); o.z=f2bf(v.z); o.w=f2bf(v.w);
  *(ushort4*)(w3b + idx4) = o;
}
// ctxb[b][s][c] bf16 from ctx[s][b][c]
__global__ __launch_bounds__(256) void k_ctxT(const float* __restrict__ ctx, ushort* __restrict__ ctxb){
  int idx4 = (blockIdx.x*256 + threadIdx.x) * 4;       // 64*256*1024
  int c = idx4 & 1023, s = (idx4 >> 10) & 255, b = idx4 >> 18;
  float4 v = *(const float4*)(ctx + (s*64 + b)*1024 + c);
  ushort4 o; o.x=f2bf(v.x); o.y=f2bf(v.y); o.z=f2bf(v.z); o.w=f2bf(v.w);
  *(ushort4*)(ctxb + idx4) = o;
}
// xb[t][b][k] bf16 from input[b][t][k]
__global__ __launch_bounds__(256) void k_xb(const float* __restrict__ inp, ushort* __restrict__ xb){
  int idx4 = (blockIdx.x*256 + threadIdx.x) * 4;       // 256*64*512
  int k = idx4 & 511, b = (idx4 >> 9) & 63, t = idx4 >> 15;
  float4 v = *(const float4*)(inp + (b*256 + t)*512 + k);
  ushort4 o; o.x=f2bf(v.x); o.y=f2bf(v.y); o.z=f2bf(v.z); o.w=f2bf(v.w);
  *(ushort4*)(xb + idx4) = o;
}
// i2aT[n][k] bf16 from i2a[k][n]
__global__ __launch_bounds__(256) void k_i2aT(const float* __restrict__ i2a, ushort* __restrict__ i2aT){
  int idx = blockIdx.x*256 + threadIdx.x;              // 512*1024
  int n = idx & 1023, k = idx >> 10;
  i2aT[n*512 + k] = f2bf(i2a[k*1024 + n]);
}
__global__ __launch_bounds__(256) void k_cvthx(const float* __restrict__ hx, ushort* __restrict__ hxbbf){
  int i4 = (blockIdx.x*256 + threadIdx.x)*4;
  float4 v = ld4(hx + i4);
  ushort4 o; o.x=f2bf(v.x); o.y=f2bf(v.y); o.z=f2bf(v.z); o.w=f2bf(v.w);
  *(ushort4*)(hxbbf + i4) = o;
}

// ============ prep: pc GEMM (f32 in, bf16 out) ============
__global__ __launch_bounds__(256) void k_pc(const float* __restrict__ ctxp, const float* __restrict__ c2a,
                                            const float* __restrict__ bc, ushort* __restrict__ pcb){
  __shared__ __align__(16) float As[32][68];
  __shared__ __align__(16) float Bs[32][68];
  const int tid = threadIdx.x;
  const int m0 = blockIdx.x * 64;
  const int n0 = blockIdx.y * 64;
  const int tx = tid & 15, ty = tid >> 4;
  float acc[4][4] = {};
  for (int k0 = 0; k0 < 1024; k0 += 32){
#pragma unroll
    for (int l = 0; l < 8; ++l){
      int idx = l*256 + tid; int m = idx >> 5, k = idx & 31;
      As[k][m] = ctxp[(m0+m)*1024 + k0 + k];
    }
#pragma unroll
    for (int l = 0; l < 8; ++l){
      int idx = l*256 + tid; int k = idx >> 6, n = idx & 63;
      Bs[k][n] = c2a[(k0+k)*1024 + n0 + n];
    }
    __syncthreads();
#pragma unroll
    for (int k = 0; k < 32; ++k){
      float4 a4 = *(const float4*)&As[k][4*ty];
      float4 b4 = *(const float4*)&Bs[k][4*tx];
      float av[4] = {a4.x, a4.y, a4.z, a4.w};
      float bv[4] = {b4.x, b4.y, b4.z, b4.w};
#pragma unroll
      for (int i = 0; i < 4; ++i)
#pragma unroll
        for (int j = 0; j < 4; ++j) acc[i][j] = fmaf(av[i], bv[j], acc[i][j]);
    }
    __syncthreads();
  }
#pragma unroll
  for (int i = 0; i < 4; ++i){
    int m = m0 + 4*ty + i;
    int n = n0 + 4*tx;
    ushort4 o;
    o.x = f2bf(acc[i][0] + bc[n]);
    o.y = f2bf(acc[i][1] + bc[n+1]);
    o.z = f2bf(acc[i][2] + bc[n+2]);
    o.w = f2bf(acc[i][3] + bc[n+3]);
    *(ushort4*)(pcb + m*1024 + n) = o;
  }
}

// ============ per-step MFMA GEMMs ============
// gates1 partial: g1p[kh][m][n] = sum_{k in half} A[m][k]*w1b[n][k]
// block: 128 thr = 2 waves; wave w -> 16 cols; 4 row-groups of 16 -> 64 rows.
__global__ __launch_bounds__(128) void k_gates1(const ushort* __restrict__ xb, const ushort* __restrict__ hxbf,
                                                const ushort* __restrict__ w1b, float* __restrict__ g1p, int t){
  const int lane = threadIdx.x & 63;
  const int w = threadIdx.x >> 6;
  const int kh = blockIdx.y;
  const int ncol = blockIdx.x*32 + w*16 + (lane & 15);
  const int ko = (lane >> 4) << 3;
  const int row = lane & 15;
  const ushort* wp = w1b + ncol*1536 + kh*768 + ko;
  f32x4 a0 = {0.f,0.f,0.f,0.f}, a1 = a0, a2 = a0, a3 = a0;
  if (kh == 0){
    const ushort* xp = xb + (t*64 + row)*512 + ko;
#pragma unroll
    for (int it = 0; it < 16; ++it){
      short8v bf = *(const short8v*)(wp + it*32);
      short8v x0 = *(const short8v*)(xp + it*32);
      short8v x1 = *(const short8v*)(xp + it*32 + 16*512);
      short8v x2 = *(const short8v*)(xp + it*32 + 32*512);
      short8v x3 = *(const short8v*)(xp + it*32 + 48*512);
      a0 = MFMA(x0, bf, a0); a1 = MFMA(x1, bf, a1); a2 = MFMA(x2, bf, a2); a3 = MFMA(x3, bf, a3);
    }
    const ushort* hp = hxbf + row*1024 + ko;
#pragma unroll
    for (int it = 0; it < 8; ++it){
      short8v bf = *(const short8v*)(wp + (16+it)*32);
      short8v x0 = *(const short8v*)(hp + it*32);
      short8v x1 = *(const short8v*)(hp + it*32 + 16*1024);
      short8v x2 = *(const short8v*)(hp + it*32 + 32*1024);
      short8v x3 = *(const short8v*)(hp + it*32 + 48*1024);
      a0 = MFMA(x0, bf, a0); a1 = MFMA(x1, bf, a1); a2 = MFMA(x2, bf, a2); a3 = MFMA(x3, bf, a3);
    }
  } else {
    const ushort* hp = hxbf + row*1024 + 256 + ko;
#pragma unroll
    for (int it = 0; it < 24; ++it){
      short8v bf = *(const short8v*)(wp + it*32);
      short8v x0 = *(const short8v*)(hp + it*32);
      short8v x1 = *(const short8v*)(hp + it*32 + 16*1024);
      short8v x2 = *(const short8v*)(hp + it*32 + 32*1024);
      short8v x3 = *(const short8v*)(hp + it*32 + 48*1024);
      a0 = MFMA(x0, bf, a0); a1 = MFMA(x1, bf, a1); a2 = MFMA(x2, bf, a2); a3 = MFMA(x3, bf, a3);
    }
  }
  float* op = g1p + kh*(64*4096) + ncol;
  const int mb = (lane >> 4) * 4;
#pragma unroll
  for (int r = 0; r < 4; ++r){
    op[(mb + r)*4096]      = a0[r];
    op[(16 + mb + r)*4096] = a1[r];
    op[(32 + mb + r)*4096] = a2[r];
    op[(48 + mb + r)*4096] = a3[r];
  }
}

// hyproj partial: hyp[kh][m][n] (n<5120). n<1024,kh==1 adds x_t@i2a (projected_input fold-in).
__global__ __launch_bounds__(128) void k_hyproj(const ushort* __restrict__ hybf, const ushort* __restrict__ w2b,
                                                const ushort* __restrict__ xb, const ushort* __restrict__ i2aT,
                                                float* __restrict__ hyp, int t){
  const int lane = threadIdx.x & 63;
  const int w = threadIdx.x >> 6;
  const int kh = blockIdx.y;
  const int ncol = blockIdx.x*32 + w*16 + (lane & 15);
  const int ko = (lane >> 4) << 3;
  const int row = lane & 15;
  const ushort* wp = w2b + ncol*1024 + kh*512 + ko;
  const ushort* hp = hybf + row*1024 + kh*512 + ko;
  f32x4 a0 = {0.f,0.f,0.f,0.f}, a1 = a0, a2 = a0, a3 = a0;
#pragma unroll
  for (int it = 0; it < 16; ++it){
    short8v bf = *(const short8v*)(wp + it*32);
    short8v x0 = *(const short8v*)(hp + it*32);
    short8v x1 = *(const short8v*)(hp + it*32 + 16*1024);
    short8v x2 = *(const short8v*)(hp + it*32 + 32*1024);
    short8v x3 = *(const short8v*)(hp + it*32 + 48*1024);
    a0 = MFMA(x0, bf, a0); a1 = MFMA(x1, bf, a1); a2 = MFMA(x2, bf, a2); a3 = MFMA(x3, bf, a3);
  }
  if (kh == 1 && ncol < 1024){
    const ushort* ip = i2aT + ncol*512 + ko;
    const ushort* xp = xb + (t*64 + row)*512 + ko;
#pragma unroll
    for (int it = 0; it < 16; ++it){
      short8v bf = *(const short8v*)(ip + it*32);
      short8v x0 = *(const short8v*)(xp + it*32);
      short8v x1 = *(const short8v*)(xp + it*32 + 16*512);
      short8v x2 = *(const short8v*)(xp + it*32 + 32*512);
      short8v x3 = *(const short8v*)(xp + it*32 + 48*512);
      a0 = MFMA(x0, bf, a0); a1 = MFMA(x1, bf, a1); a2 = MFMA(x2, bf, a2); a3 = MFMA(x3, bf, a3);
    }
  }
  float* op = hyp + kh*(64*5120) + ncol;
  const int mb = (lane >> 4) * 4;
#pragma unroll
  for (int r = 0; r < 4; ++r){
    op[(mb + r)*5120]      = a0[r];
    op[(16 + mb + r)*5120] = a1[r];
    op[(32 + mb + r)*5120] = a2[r];
    op[(48 + mb + r)*5120] = a3[r];
  }
}

// gates2 partial: g2p[kh][m][n] = sum wctx[m][k]*w3b[n][k]
__global__ __launch_bounds__(128) void k_gates2(const ushort* __restrict__ wctxbf, const ushort* __restrict__ w3b,
                                                float* __restrict__ g2p){
  const int lane = threadIdx.x & 63;
  const int w = threadIdx.x >> 6;
  const int kh = blockIdx.y;
  const int ncol = blockIdx.x*32 + w*16 + (lane & 15);
  const int ko = (lane >> 4) << 3;
  const int row = lane & 15;
  const ushort* wp = w3b + ncol*1024 + kh*512 + ko;
  const ushort* ap = wctxbf + row*1024 + kh*512 + ko;
  f32x4 a0 = {0.f,0.f,0.f,0.f}, a1 = a0, a2 = a0, a3 = a0;
#pragma unroll
  for (int it = 0; it < 16; ++it){
    short8v bf = *(const short8v*)(wp + it*32);
    short8v x0 = *(const short8v*)(ap + it*32);
    short8v x1 = *(const short8v*)(ap + it*32 + 16*1024);
    short8v x2 = *(const short8v*)(ap + it*32 + 32*1024);
    short8v x3 = *(const short8v*)(ap + it*32 + 48*1024);
    a0 = MFMA(x0, bf, a0); a1 = MFMA(x1, bf, a1); a2 = MFMA(x2, bf, a2); a3 = MFMA(x3, bf, a3);
  }
  float* op = g2p + kh*(64*4096) + ncol;
  const int mb = (lane >> 4) * 4;
#pragma unroll
  for (int r = 0; r < 4; ++r){
    op[(mb + r)*4096]      = a0[r];
    op[(16 + mb + r)*4096] = a1[r];
    op[(32 + mb + r)*4096] = a2[r];
    op[(48 + mb + r)*4096] = a3[r];
  }
}

// ============ pointwise ============
__global__ __launch_bounds__(256) void k_lstm1(const float* __restrict__ g1p, const float* __restrict__ cxb,
                                               const float* __restrict__ ib1, const float* __restrict__ hb1,
                                               float* __restrict__ cym, ushort* __restrict__ hybf){
  int i4 = (blockIdx.x*256 + threadIdx.x)*4;
  int b = i4 >> 10, h = i4 & 1023;
  const float* p0 = g1p + b*4096;
  const float* p1 = g1p + 64*4096 + b*4096;
#define LOADG1(off) ({ float4 A=ld4(p0+(off)); float4 Bv=ld4(p1+(off)); float4 C=ld4(ib1+(off)); float4 D=ld4(hb1+(off)); \
                       make_float4(A.x+Bv.x+C.x+D.x, A.y+Bv.y+C.y+D.y, A.z+Bv.z+C.z+D.z, A.w+Bv.w+C.w+D.w); })
  float4 gi = LOADG1(h);
  float4 gf = LOADG1(h+1024);
  float4 gg = LOADG1(h+2048);
  float4 go = LOADG1(h+3072);
#undef LOADG1
  float4 cx4 = ld4(cxb + i4);
  float c0 = sigf(gf.x)*cx4.x + sigf(gi.x)*tanhfast(gg.x);
  float c1 = sigf(gf.y)*cx4.y + sigf(gi.y)*tanhfast(gg.y);
  float c2 = sigf(gf.z)*cx4.z + sigf(gi.z)*tanhfast(gg.z);
  float c3 = sigf(gf.w)*cx4.w + sigf(gi.w)*tanhfast(gg.w);
  *(float4*)(cym + i4) = make_float4(c0,c1,c2,c3);
  ushort4 o;
  o.x = f2bf(sigf(go.x)*tanhfast(c0));
  o.y = f2bf(sigf(go.y)*tanhfast(c1));
  o.z = f2bf(sigf(go.z)*tanhfast(c2));
  o.w = f2bf(sigf(go.w)*tanhfast(c3));
  *(ushort4*)(hybf + i4) = o;
}

__global__ __launch_bounds__(256) void k_lstm2(const float* __restrict__ g2p, const float* __restrict__ hyp,
                                               const float* __restrict__ cym,
                                               const float* __restrict__ ib2, const float* __restrict__ hb2,
                                               float* __restrict__ out, float* __restrict__ hxb,
                                               ushort* __restrict__ hxbbf, float* __restrict__ cxb, int t){
  int i4 = (blockIdx.x*256 + threadIdx.x)*4;
  int b = i4 >> 10, h = i4 & 1023;
  const float* p0 = g2p + b*4096;
  const float* p1 = g2p + 64*4096 + b*4096;
  const float* q0 = hyp + b*5120 + 1024;
  const float* q1 = hyp + 64*5120 + b*5120 + 1024;
#define LOADG2(off) ({ float4 A=ld4(p0+(off)); float4 Bv=ld4(p1+(off)); float4 C=ld4(q0+(off)); float4 D=ld4(q1+(off)); \
                       float4 E=ld4(ib2+(off)); float4 F=ld4(hb2+(off)); \
                       make_float4(A.x+Bv.x+C.x+D.x+E.x+F.x, A.y+Bv.y+C.y+D.y+E.y+F.y, \
                                   A.z+Bv.z+C.z+D.z+E.z+F.z, A.w+Bv.w+C.w+D.w+E.w+F.w); })
  float4 gi = LOADG2(h);
  float4 gf = LOADG2(h+1024);
  float4 gg = LOADG2(h+2048);
  float4 go = LOADG2(h+3072);
#undef LOADG2
  float4 cm4 = ld4(cym + i4);
  float c0 = sigf(gf.x)*cm4.x + sigf(gi.x)*tanhfast(gg.x);
  float c1 = sigf(gf.y)*cm4.y + sigf(gi.y)*tanhfast(gg.y);
  float c2 = sigf(gf.z)*cm4.z + sigf(gi.z)*tanhfast(gg.z);
  float c3 = sigf(gf.w)*cm4.w + sigf(gi.w)*tanhfast(gg.w);
  float h0 = sigf(go.x)*tanhfast(c0);
  float h1 = sigf(go.y)*tanhfast(c1);
  float h2 = sigf(go.z)*tanhfast(c2);
  float h3 = sigf(go.w)*tanhfast(c3);
  float4 h4 = make_float4(h0,h1,h2,h3);
  *(float4*)(out + t*65536 + i4) = h4;
  *(float4*)(hxb + i4) = h4;
  *(float4*)(cxb + i4) = make_float4(c0,c1,c2,c3);
  ushort4 o; o.x=f2bf(h0); o.y=f2bf(h1); o.z=f2bf(h2); o.w=f2bf(h3);
  *(ushort4*)(hxbbf + i4) = o;
}

// ============ attention ============
// logits[b][s] = sum_c tanh(pcb[s,b,c] + q0[b,c] + q1[b,c]) * r[c]
__global__ __launch_bounds__(256) void k_logits(const ushort* __restrict__ pcb, const float* __restrict__ hyp,
                                                const float* __restrict__ r2a, float* __restrict__ logits){
  const int w = threadIdx.x >> 6, lane = threadIdx.x & 63;
  const int p = blockIdx.x*4 + w;
  const int s = p >> 6, b = p & 63;
  const ushort* pp = pcb + (s*64 + b)*1024;
  const float* q0 = hyp + b*5120;
  const float* q1 = hyp + 64*5120 + b*5120;
  float acc = 0.0f;
#pragma unroll
  for (int half = 0; half < 2; ++half){
    int cb = lane*8 + half*512;
    uint4 pv = *(const uint4*)(pp + cb);
    float4 qa0 = ld4(q0+cb), qa1 = ld4(q0+cb+4);
    float4 qb0 = ld4(q1+cb), qb1 = ld4(q1+cb+4);
    float4 r0 = ld4(r2a+cb), r1 = ld4(r2a+cb+4);
    acc = fmaf(tanhfast(u2f(pv.x << 16)         + qa0.x + qb0.x), r0.x, acc);
    acc = fmaf(tanhfast(u2f(pv.x & 0xffff0000u) + qa0.y + qb0.y), r0.y, acc);
    acc = fmaf(tanhfast(u2f(pv.y << 16)         + qa0.z + qb0.z), r0.z, acc);
    acc = fmaf(tanhfast(u2f(pv.y & 0xffff0000u) + qa0.w + qb0.w), r0.w, acc);
    acc = fmaf(tanhfast(u2f(pv.z << 16)         + qa1.x + qb1.x), r1.x, acc);
    acc = fmaf(tanhfast(u2f(pv.z & 0xffff0000u) + qa1.y + qb1.y), r1.y, acc);
    acc = fmaf(tanhfast(u2f(pv.w << 16)         + qa1.z + qb1.z), r1.z, acc);
    acc = fmaf(tanhfast(u2f(pv.w & 0xffff0000u) + qa1.w + qb1.w), r1.w, acc);
  }
#pragma unroll
  for (int off = 32; off; off >>= 1) acc += __shfl_xor(acc, off);
  if (lane == 0) logits[b*256 + s] = acc;
}

// softmax (redundant per chunk) + partial wctx over a 32-s chunk (ctxb bf16 [b][s][c])
__global__ __launch_bounds__(256) void k_attnout(const float* __restrict__ logits, const ushort* __restrict__ ctxb,
                                                 float* __restrict__ partial){
  __shared__ float red[256];
  __shared__ float sm[256];
  __shared__ float al[32];
  const int bi = blockIdx.x >> 3, ch = blockIdx.x & 7;
  const int tid = threadIdx.x;
  float l = logits[bi*256 + tid];
  red[tid] = l; __syncthreads();
  for (int s = 128; s; s >>= 1){ if (tid < s) red[tid] = fmaxf(red[tid], red[tid+s]); __syncthreads(); }
  float mx = red[0]; __syncthreads();
  float e = __expf(l - mx);
  sm[tid] = e; red[tid] = e; __syncthreads();
  for (int s = 128; s; s >>= 1){ if (tid < s) red[tid] += red[tid+s]; __syncthreads(); }
  float inv = rcpf_(red[0]);
  if (tid < 32) al[tid] = sm[ch*32 + tid] * inv;
  __syncthreads();
  const int c0 = tid * 4;
  const ushort* cp = ctxb + (bi*256 + ch*32)*1024 + c0;
  float a0=0.f, a1=0.f, a2=0.f, a3=0.f;
#pragma unroll 4
  for (int s = 0; s < 32; ++s){
    ushort4 v = *(const ushort4*)(cp + s*1024);
    float aw = al[s];
    a0 = fmaf(aw, bf2f(v.x), a0);
    a1 = fmaf(aw, bf2f(v.y), a1);
    a2 = fmaf(aw, bf2f(v.z), a2);
    a3 = fmaf(aw, bf2f(v.w), a3);
  }
  float4 o; o.x=a0; o.y=a1; o.z=a2; o.w=a3;
  *(float4*)(partial + (ch*64 + bi)*1024 + c0) = o;
}

// reduce 8 partials -> wctx (bf16)
__global__ __launch_bounds__(256) void k_wctxred(const float* __restrict__ partial, ushort* __restrict__ wctxbf){
  int i4 = (blockIdx.x*256 + threadIdx.x) * 4;
  float4 s = *(const float4*)(partial + i4);
#pragma unroll
  for (int ch = 1; ch < 8; ++ch){
    float4 v = *(const float4*)(partial + ch*65536 + i4);
    s.x += v.x; s.y += v.y; s.z += v.z; s.w += v.w;
  }
  ushort4 o; o.x=f2bf(s.x); o.y=f2bf(s.y); o.z=f2bf(s.z); o.w=f2bf(s.w);
  *(ushort4*)(wctxbf + i4) = o;
}

extern "C" void kernel_launch(void* const* d_in, const int* in_sizes, int n_in,
                              void* d_out, int out_size, void* d_ws, size_t ws_size,
                              hipStream_t stream) {
  const float* input = (const float*)d_in[0];
  const float* hx    = (const float*)d_in[1];
  const float* cx    = (const float*)d_in[2];
  const float* ctxp  = (const float*)d_in[3];
  const float* iw1   = (const float*)d_in[4];
  const float* hw1   = (const float*)d_in[5];
  const float* ib1   = (const float*)d_in[6];
  const float* hb1   = (const float*)d_in[7];
  const float* iw2   = (const float*)d_in[8];
  const float* hw2   = (const float*)d_in[9];
  const float* ib2   = (const float*)d_in[10];
  const float* hb2   = (const float*)d_in[11];
  const float* c2a   = (const float*)d_in[12];
  const float* b_c2a = (const float*)d_in[13];
  const float* h2a   = (const float*)d_in[14];
  const float* i2a   = (const float*)d_in[15];
  const float* r2a   = (const float*)d_in[16];
  float* out = (float*)d_out;

  char* base = (char*)d_ws;
  ushort* pcb    = (ushort*)(base);                     // 33,554,432
  ushort* ctxb   = (ushort*)(base + 33554432);          // 33,554,432
  ushort* xb     = (ushort*)(base + 67108864);          // 16,777,216
  ushort* w1b    = (ushort*)(base + 83886080);          // 12,582,912
  ushort* w2b    = (ushort*)(base + 96468992);          // 10,485,760
  ushort* w3b    = (ushort*)(base + 106954752);         //  8,388,608
  ushort* i2aT   = (ushort*)(base + 115343360);         //  1,048,576
  float*  g1p    = (float*)(base + 116391936);          //  2,097,152
  float*  hyp    = (float*)(base + 118489088);          //  2,621,440
  float*  g2p    = (float*)(base + 121110528);          //  2,097,152
  float*  cym    = (float*)(base + 123207680);          //    262,144
  float*  hxb    = (float*)(base + 123469824);          //    262,144
  float*  cxb    = (float*)(base + 123731968);          //    262,144
  ushort* hybf   = (ushort*)(base + 123994112);         //    131,072
  ushort* hxbbf  = (ushort*)(base + 124125184);         //    131,072
  ushort* wctxbf = (ushort*)(base + 124256256);         //    131,072
  float*  logits = (float*)(base + 124387328);          //     65,536
  float*  partial= (float*)(base + 124452864);          //  2,097,152  (end 126,550,016)

  hipMemcpyAsync(hxb, hx, 262144, hipMemcpyDeviceToDevice, stream);
  hipMemcpyAsync(cxb, cx, 262144, hipMemcpyDeviceToDevice, stream);

  k_cvthx<<<64,   256, 0, stream>>>(hx, hxbbf);
  k_w1  <<<6144,  256, 0, stream>>>(iw1, hw1, w1b);
  k_w2  <<<5120,  256, 0, stream>>>(h2a, hw2, w2b);
  k_w3  <<<4096,  256, 0, stream>>>(iw2, w3b);
  k_ctxT<<<16384, 256, 0, stream>>>(ctxp, ctxb);
  k_xb  <<<8192,  256, 0, stream>>>(input, xb);
  k_i2aT<<<2048,  256, 0, stream>>>(i2a, i2aT);
  k_pc  <<<dim3(256,16), 256, 0, stream>>>(ctxp, c2a, b_c2a, pcb);

  for (int t = 0; t < 256; ++t){
    k_gates1 <<<dim3(128,2), 128, 0, stream>>>(xb, hxbbf, w1b, g1p, t);
    k_lstm1  <<<64,  256, 0, stream>>>(g1p, cxb, ib1, hb1, cym, hybf);
    k_hyproj <<<dim3(160,2), 128, 0, stream>>>(hybf, w2b, xb, i2aT, hyp, t);
    k_logits <<<4096,256, 0, stream>>>(pcb, hyp, r2a, logits);
    k_attnout<<<512, 256, 0, stream>>>(logits, ctxb, partial);
    k_wctxred<<<64,  256, 0, stream>>>(partial, wctxbf);
    k_gates2 <<<dim3(128,2), 128, 0, stream>>>(wctxbf, w3b, g2p);
    k_lstm2  <<<64,  256, 0, stream>>>(g2p, hyp, cym, ib2, hb2, out, hxb, hxbbf, cxb, t);
  }

  hipMemcpyAsync(out + 16777216,         hxb, 262144, hipMemcpyDeviceToDevice, stream);
  hipMemcpyAsync(out + 16777216 + 65536, cxb, 262144, hipMemcpyDeviceToDevice, stream);
}